// Round 13
// baseline (35968.658 us; speedup 1.0000x reference)
//
#include <hip/hip_runtime.h>
#include <hip/hip_bf16.h>

#define S_LEN 8192
#define CLEN 16
#define WDIM 256
#define CDIM 64
#define CHID 128
#define WHID 512
#define GDIM 2048   // 4*WHID
#define NTAG 64
#define KDIM 384    // WDIM + CHID
#define NWG 32      // workgroups in sequential kernel

typedef unsigned long long u64;

__device__ __forceinline__ float sigmoidf_(float x) {
  return 1.0f / (1.0f + __expf(-x));
}
__device__ __forceinline__ float tanhf_(float x) {
  // safe tanh: 1 - 2/(e^{2x}+1); correct limits at +-inf without NaN
  return 1.0f - 2.0f / (__expf(2.0f * x) + 1.0f);
}

// ---------------------------------------------------------------------------
// K1: batched char LSTM (R3 verbatim) + hbuf zeroing folded into block 0
// (replaces the hipMemsetAsync graph node; kernel boundary orders it before
// the sequential kernel).
// ---------------------------------------------------------------------------
__global__ __launch_bounds__(256)
void char_lstm_kernel(const int* __restrict__ chars, const int* __restrict__ lengths,
                      const float* __restrict__ emb, const float* __restrict__ Wih,
                      const float* __restrict__ Whh, const float* __restrict__ bih,
                      const float* __restrict__ bhh, float* __restrict__ cf,
                      u64* hbuf)
{
  __shared__ float xs[16][CDIM];
  __shared__ float hsm[16][CHID];
  __shared__ int cidx[16];
  __shared__ int lens[16];
  const int tid = threadIdx.x;
  const int grp = tid >> 7;      // 0..1 (word group)
  const int j = tid & 127;       // hidden index
  const int wb = blockIdx.x * 16;

  if (blockIdx.x == 0) {         // zero the 2x512 tagged slots every call
    for (int i = tid; i < 2 * WHID; i += 256) hbuf[i] = 0ULL;
  }

  for (int i = tid; i < 16 * CHID; i += 256) (&hsm[0][0])[i] = 0.f;
  if (tid < 16) lens[tid] = lengths[wb + tid];
  float c[8];
#pragma unroll
  for (int w = 0; w < 8; ++w) c[w] = 0.f;
  const float bi = bih[j] + bhh[j];
  const float bf = bih[CHID + j] + bhh[CHID + j];
  const float bg = bih[2 * CHID + j] + bhh[2 * CHID + j];
  const float bo = bih[3 * CHID + j] + bhh[3 * CHID + j];

  for (int t = 0; t < CLEN; ++t) {
    __syncthreads();
    if (tid < 16) cidx[tid] = chars[(wb + tid) * CLEN + t];
    __syncthreads();
    {
      int e = tid * 4;
      int wi = e >> 6;
      int k = e & 63;
      const float4 v = *(const float4*)(emb + (size_t)cidx[wi] * CDIM + k);
      *(float4*)(&xs[wi][k]) = v;
    }
    __syncthreads();
    float ai[8], af[8], ag[8], ao[8];
#pragma unroll
    for (int w = 0; w < 8; ++w) { ai[w] = bi; af[w] = bf; ag[w] = bg; ao[w] = bo; }
    // x part (K = 64)
    for (int k = 0; k < CDIM; k += 4) {
      float4 w0 = *(const float4*)(Wih + (size_t)j * CDIM + k);
      float4 w1 = *(const float4*)(Wih + (size_t)(CHID + j) * CDIM + k);
      float4 w2 = *(const float4*)(Wih + (size_t)(2 * CHID + j) * CDIM + k);
      float4 w3 = *(const float4*)(Wih + (size_t)(3 * CHID + j) * CDIM + k);
#pragma unroll
      for (int s = 0; s < 4; ++s) {
        float wiv = (&w0.x)[s], wfv = (&w1.x)[s], wgv = (&w2.x)[s], wov = (&w3.x)[s];
#pragma unroll
        for (int w = 0; w < 8; ++w) {
          float xv = xs[grp * 8 + w][k + s];   // wave-uniform -> LDS broadcast
          ai[w] = fmaf(wiv, xv, ai[w]);
          af[w] = fmaf(wfv, xv, af[w]);
          ag[w] = fmaf(wgv, xv, ag[w]);
          ao[w] = fmaf(wov, xv, ao[w]);
        }
      }
    }
    // h part (K = 128)
    for (int k = 0; k < CHID; k += 4) {
      float4 w0 = *(const float4*)(Whh + (size_t)j * CHID + k);
      float4 w1 = *(const float4*)(Whh + (size_t)(CHID + j) * CHID + k);
      float4 w2 = *(const float4*)(Whh + (size_t)(2 * CHID + j) * CHID + k);
      float4 w3 = *(const float4*)(Whh + (size_t)(3 * CHID + j) * CHID + k);
#pragma unroll
      for (int s = 0; s < 4; ++s) {
        float wiv = (&w0.x)[s], wfv = (&w1.x)[s], wgv = (&w2.x)[s], wov = (&w3.x)[s];
#pragma unroll
        for (int w = 0; w < 8; ++w) {
          float hv = hsm[grp * 8 + w][k + s];
          ai[w] = fmaf(wiv, hv, ai[w]);
          af[w] = fmaf(wfv, hv, af[w]);
          ag[w] = fmaf(wgv, hv, ag[w]);
          ao[w] = fmaf(wov, hv, ao[w]);
        }
      }
    }
    __syncthreads();
#pragma unroll
    for (int w = 0; w < 8; ++w) {
      if (t < lens[grp * 8 + w]) {
        float iv = sigmoidf_(ai[w]);
        float fv = sigmoidf_(af[w]);
        float gv = tanhf_(ag[w]);
        float ov = sigmoidf_(ao[w]);
        c[w] = fv * c[w] + iv * gv;
        hsm[grp * 8 + w][j] = ov * tanhf_(c[w]);
      }
    }
  }
#pragma unroll
  for (int w = 0; w < 8; ++w)
    cf[(size_t)(wb + grp * 8 + w) * CHID + j] = c[w];   // feature = final CELL state
}

// ---------------------------------------------------------------------------
// K2: G_x[t][g] = [word_emb[x[t]] | char_feat[t]] @ w_Wih^T + (bih+bhh)
// (R3 verbatim -- the R12 fold of this into the recurrence regressed.)
// ---------------------------------------------------------------------------
#define BM 64
#define BN 64
#define BK 32
__global__ __launch_bounds__(256)
void gx_gemm_kernel(const int* __restrict__ x, const float* __restrict__ word_emb,
                    const float* __restrict__ char_feat, const float* __restrict__ Wih,
                    const float* __restrict__ bih, const float* __restrict__ bhh,
                    float* __restrict__ Gx)
{
  __shared__ float As[BK][BM + 1];
  __shared__ float Bs[BK][BN + 1];
  __shared__ int xidx[BM];
  const int tid = threadIdx.x;
  const int tx = tid & 15, ty = tid >> 4;
  const int m0 = blockIdx.y * BM;
  const int n0 = blockIdx.x * BN;
  if (tid < BM) xidx[tid] = x[m0 + tid];
  float acc[4][4] = {};
  for (int k0 = 0; k0 < KDIM; k0 += BK) {
    __syncthreads();
    {
      int i = tid >> 5;
      int kk = tid & 31;
#pragma unroll
      for (int l = 0; l < 8; ++l) {
        int row = i + l * 8;
        int k = k0 + kk;
        int tt = m0 + row;
        float v = (k < WDIM) ? word_emb[(size_t)xidx[row] * WDIM + k]
                             : char_feat[(size_t)tt * CHID + (k - WDIM)];
        As[kk][row] = v;
      }
    }
    {
      int jjj = tid >> 5;
      int kk = tid & 31;
#pragma unroll
      for (int l = 0; l < 8; ++l) {
        int col = jjj + l * 8;
        Bs[kk][col] = Wih[(size_t)(n0 + col) * KDIM + k0 + kk];
      }
    }
    __syncthreads();
#pragma unroll
    for (int kk = 0; kk < BK; ++kk) {
      float a[4], b[4];
#pragma unroll
      for (int m = 0; m < 4; ++m) a[m] = As[kk][ty * 4 + m];
#pragma unroll
      for (int n = 0; n < 4; ++n) b[n] = Bs[kk][tx * 4 + n];
#pragma unroll
      for (int m = 0; m < 4; ++m)
#pragma unroll
        for (int n = 0; n < 4; ++n)
          acc[m][n] = fmaf(a[m], b[n], acc[m][n]);
    }
  }
#pragma unroll
  for (int n = 0; n < 4; ++n) {
    int g = n0 + tx * 4 + n;
    float bias = bih[g] + bhh[g];
#pragma unroll
    for (int m = 0; m < 4; ++m) {
      int tt = m0 + ty * 4 + m;
      Gx[(size_t)tt * GDIM + g] = acc[m][n] + bias;
    }
  }
}

// ---------------------------------------------------------------------------
// K3: sequential word LSTM, v13 = R3 (proven 13.88 ms) + fused output head.
//
// Unchanged from R3: 32 WGs, agent-scope tagged-slot sync (atomic u64, no
// tearing), Gx load issued before the poll, L2-streamed wl[128] weights
// (proven faster than LDS-resident at 1 WG/CU), one barrier/step, wave0
// finalize + publish. NO new inter-block sync (R5/R11 lesson).
//
// New: after the barrier of step t, h_lds[t&1] holds the COMPLETE h_{t-1}
// (all 4 waves staged it). The WG with (t-1)%32==wg computes the final
// linear+log_softmax row out[t-1] right there, on ONE otherwise-idle wave
// (rotating 1->2->3 every 32-step window so each wave is hit only every 96
// steps; its ~1.5-3K cy of lin_W streaming hides in that wave's ~1 us poll
// shadow). h_lds is double-buffered by parity: h_lds[par] is next
// overwritten only at step t+2, i.e. after barrier(t+1), which the
// tag-computing wave reaches only after finishing -- race-free.
// Row 8191 is computed in a wg-31 epilogue from the tag-8192 publish.
// This deletes the tag kernel, the hs buffer (16 MB), and per-step hs
// stores: two fewer graph nodes, less traffic, zero added waits.
// ---------------------------------------------------------------------------
__global__ __launch_bounds__(256, 1)
void word_lstm_seq(const float* __restrict__ Whh, const float* __restrict__ Gx,
                   const float* __restrict__ linW, const float* __restrict__ linb,
                   float* __restrict__ out, u64* hbuf)
{
  __shared__ float h_lds[2][WHID];
  __shared__ float red[2][256];
  const int tid  = threadIdx.x;
  const int wg   = blockIdx.x;
  const int cc   = tid >> 6;     // k-chunk 0..3 (one per wave)
  const int lane = tid & 63;
  const int kb   = cc * 128;
  const int grow = (lane >> 4) * WHID + wg * 16 + (lane & 15);

  // per-lane weight chunk (R3 codegen: compiler streams from L2 in-loop --
  // measured faster than LDS-resident at 1 WG/CU in R9)
  float wl[128];
  {
    const float* wsrc = Whh + (size_t)grow * WHID + kb;
#pragma unroll
    for (int k = 0; k < 128; ++k) wl[k] = wsrc[k];
  }

  float c_state = 0.f;   // lanes<16 of wave 0 use

  for (int t = 0; t < S_LEN; ++t) {
    const int par = t & 1;
    float gxv = 0.f;
    if (tid < 64)
      gxv = Gx[(size_t)t * GDIM + grow];   // issued before poll; latency hides
    // ---- poll own 2 tagged slots (atomic u64: tag+value arrive together) ----
    float v0 = 0.f, v1 = 0.f;
    if (t > 0) {
      const u64* ps = hbuf + (size_t)par * WHID + kb + 2 * lane;
      const unsigned want = (unsigned)t;
      u64 a, b;
      do {
        a = __hip_atomic_load(ps + 0, __ATOMIC_RELAXED, __HIP_MEMORY_SCOPE_AGENT);
        b = __hip_atomic_load(ps + 1, __ATOMIC_RELAXED, __HIP_MEMORY_SCOPE_AGENT);
      } while (((unsigned)(a >> 32) != want) | ((unsigned)(b >> 32) != want));
      v0 = __uint_as_float((unsigned)a);
      v1 = __uint_as_float((unsigned)b);
    }
    *(float2*)(&h_lds[par][kb + 2 * lane]) = make_float2(v0, v1);
    __threadfence_block();
    // ---- matvec: weights in-loop from L2, h broadcast from LDS ----
    float acc = 0.f;
#pragma unroll
    for (int g = 0; g < 32; ++g) {
      float4 hv = *(const float4*)(&h_lds[par][kb + 4 * g]);
      acc = fmaf(wl[4 * g + 0], hv.x, acc);
      acc = fmaf(wl[4 * g + 1], hv.y, acc);
      acc = fmaf(wl[4 * g + 2], hv.z, acc);
      acc = fmaf(wl[4 * g + 3], hv.w, acc);
    }
    red[par][tid] = acc;
    __syncthreads();   // the ONLY barrier per step; h_lds[par] now complete
    if (tid < 64) {
      // ---- wave0: finalize + publish (R3 verbatim, minus hs store) ----
      const float* rp = red[par];
      float s = rp[tid] + rp[64 + tid] + rp[128 + tid] + rp[192 + tid] + gxv;
      float act = ((tid >> 4) == 2) ? tanhf_(s) : sigmoidf_(s);
      int jj = tid & 15;
      float iv = __shfl(act, jj);
      float fv = __shfl(act, 16 + jj);
      float gv = __shfl(act, 32 + jj);
      float ov = __shfl(act, 48 + jj);
      if (tid < 16) {
        c_state = fv * c_state + iv * gv;
        float hv = ov * tanhf_(c_state);
        const int hidx = wg * 16 + tid;
        const u64 pkt = ((u64)(unsigned)(t + 1) << 32) | (u64)__float_as_uint(hv);
        (void)__hip_atomic_exchange(&hbuf[(size_t)((t + 1) & 1) * WHID + hidx],
                                    pkt, __ATOMIC_RELAXED,
                                    __HIP_MEMORY_SCOPE_AGENT);
      }
    } else if (t > 0 && ((t - 1) & 31) == wg &&
               cc == 1 + (((t - 1) >> 5) % 3)) {
      // ---- fused output head: row t-1 from h_lds[par] (== h_{t-1}) ----
      const float* hrow = h_lds[par];                 // lane-uniform reads
      const float* wrow = linW + (size_t)lane * WHID; // per-lane tag row
      float a2 = linb[lane];
      for (int k = 0; k < WHID; k += 4) {
        float4 wv = *(const float4*)(wrow + k);
        a2 = fmaf(wv.x, hrow[k + 0], a2);
        a2 = fmaf(wv.y, hrow[k + 1], a2);
        a2 = fmaf(wv.z, hrow[k + 2], a2);
        a2 = fmaf(wv.w, hrow[k + 3], a2);
      }
      float m = a2;
#pragma unroll
      for (int off = 32; off > 0; off >>= 1) m = fmaxf(m, __shfl_xor(m, off));
      float e = __expf(a2 - m);
      float sum = e;
#pragma unroll
      for (int off = 32; off > 0; off >>= 1) sum += __shfl_xor(sum, off);
      out[(size_t)(t - 1) * NTAG + lane] = (a2 - m) - __logf(sum);
    }
  }

  // ---- epilogue: row 8191 ((8191 & 31) == 31 -> wg 31 owns it) ----
  if (wg == 31) {
    // h_8191 was published with tag 8192 into parity 0 by every WG's wave0
    const u64* ps = hbuf + kb + 2 * lane;   // parity 0 base
    const unsigned want = (unsigned)S_LEN;
    u64 a, b;
    do {
      a = __hip_atomic_load(ps + 0, __ATOMIC_RELAXED, __HIP_MEMORY_SCOPE_AGENT);
      b = __hip_atomic_load(ps + 1, __ATOMIC_RELAXED, __HIP_MEMORY_SCOPE_AGENT);
    } while (((unsigned)(a >> 32) != want) | ((unsigned)(b >> 32) != want));
    *(float2*)(&h_lds[0][kb + 2 * lane]) =
        make_float2(__uint_as_float((unsigned)a), __uint_as_float((unsigned)b));
    __syncthreads();
    if (tid < 64) {
      const float* hrow = h_lds[0];
      const float* wrow = linW + (size_t)tid * WHID;
      float a2 = linb[tid];
      for (int k = 0; k < WHID; k += 4) {
        float4 wv = *(const float4*)(wrow + k);
        a2 = fmaf(wv.x, hrow[k + 0], a2);
        a2 = fmaf(wv.y, hrow[k + 1], a2);
        a2 = fmaf(wv.z, hrow[k + 2], a2);
        a2 = fmaf(wv.w, hrow[k + 3], a2);
      }
      float m = a2;
#pragma unroll
      for (int off = 32; off > 0; off >>= 1) m = fmaxf(m, __shfl_xor(m, off));
      float e = __expf(a2 - m);
      float sum = e;
#pragma unroll
      for (int off = 32; off > 0; off >>= 1) sum += __shfl_xor(sum, off);
      out[(size_t)(S_LEN - 1) * NTAG + tid] = (a2 - m) - __logf(sum);
    }
  }
}

extern "C" void kernel_launch(void* const* d_in, const int* in_sizes, int n_in,
                              void* d_out, int out_size, void* d_ws, size_t ws_size,
                              hipStream_t stream)
{
  const int* x          = (const int*)d_in[0];
  const int* chars      = (const int*)d_in[1];
  const int* lengths    = (const int*)d_in[2];
  const float* word_emb = (const float*)d_in[3];
  const float* char_emb = (const float*)d_in[4];
  const float* c_Wih    = (const float*)d_in[5];
  const float* c_Whh    = (const float*)d_in[6];
  const float* c_bih    = (const float*)d_in[7];
  const float* c_bhh    = (const float*)d_in[8];
  const float* w_Wih    = (const float*)d_in[9];
  const float* w_Whh    = (const float*)d_in[10];
  const float* w_bih    = (const float*)d_in[11];
  const float* w_bhh    = (const float*)d_in[12];
  const float* lin_W    = (const float*)d_in[13];
  const float* lin_b    = (const float*)d_in[14];
  float* out = (float*)d_out;

  char* ws = (char*)d_ws;
  // layout: [0,8192) hbuf (2 x 512 u64 tagged slots; zeroed by char block 0)
  //         | char_feat 4 MiB | Gx 64 MiB      (no hs buffer anymore)
  u64*   hbuf      = (u64*)ws;
  float* char_feat = (float*)(ws + 8192);
  float* Gx        = (float*)(ws + 8192 + (size_t)S_LEN * CHID * 4);

  char_lstm_kernel<<<S_LEN / 16, 256, 0, stream>>>(
      chars, lengths, char_emb, c_Wih, c_Whh, c_bih, c_bhh, char_feat, hbuf);

  dim3 g2(GDIM / BN, S_LEN / BM);
  gx_gemm_kernel<<<g2, 256, 0, stream>>>(
      x, word_emb, char_feat, w_Wih, w_bih, w_bhh, Gx);

  word_lstm_seq<<<NWG, 256, 0, stream>>>(w_Whh, Gx, lin_W, lin_b, out, hbuf);
}